// Round 3
// baseline (472.061 us; speedup 1.0000x reference)
//
#include <hip/hip_runtime.h>
#include <hip/hip_bf16.h>
#include <math.h>

#define B_  128
#define L_  196
#define F_  2048
#define H_  512
#define A_  512
#define ML_ (B_*L_)   // 25088 rows = 196 tiles of 128 exactly

typedef _Float16 half8 __attribute__((ext_vector_type(8)));
typedef _Float16 half4v __attribute__((ext_vector_type(4)));
typedef _Float16 half2v __attribute__((ext_vector_type(2)));
typedef float f32x4 __attribute__((ext_vector_type(4)));

// async 16B global->LDS (LDS dest = wave-uniform base + lane*16)
__device__ __forceinline__ void gld_lds16(const void* g, void* l) {
  __builtin_amdgcn_global_load_lds((const __attribute__((address_space(1))) void*)g,
                                   (__attribute__((address_space(3))) void*)l, 16, 0, 0);
}

// ---------------------------------------------------------------------------
// K_prep (small): 128 blocks. Wenc fp32->f16 (4 MB, 8-deep unrolled),
// dec[b][a] = b_dec+b_enc+hs·Wdec^T, zero scores.
// ---------------------------------------------------------------------------
__global__ __launch_bounds__(256) void k_prep(const float4* __restrict__ Wenc4,
                                              half4v* __restrict__ wH,
                                              const float* __restrict__ hs,
                                              const float* __restrict__ Wdec,
                                              const float* __restrict__ bdec,
                                              const float* __restrict__ benc,
                                              float* __restrict__ dec,
                                              float* __restrict__ scores) {
  const int b = blockIdx.x, t = threadIdx.x;

  {
    const int base = b * 2048 + t;
    float4 v[8];
#pragma unroll
    for (int j = 0; j < 8; j++) v[j] = Wenc4[base + j * 256];
#pragma unroll
    for (int j = 0; j < 8; j++) {
      half4v o = { (_Float16)v[j].x, (_Float16)v[j].y, (_Float16)v[j].z, (_Float16)v[j].w };
      wH[base + j * 256] = o;
    }
  }

  const int g = b * 256 + t;
  if (g < ML_) scores[g] = 0.f;

  __shared__ float h[H_];
  h[t]       = hs[b * H_ + t];
  h[t + 256] = hs[b * H_ + t + 256];
  __syncthreads();

#pragma unroll
  for (int r = 0; r < 2; r++) {
    const int a = t + r * 256;
    float acc = bdec[a] + benc[a];
    const float4* wr = (const float4*)(Wdec + (size_t)a * H_);
#pragma unroll 4
    for (int k4 = 0; k4 < H_ / 4; k4++) {
      const float4 w = wr[k4];
      acc += w.x * h[4*k4] + w.y * h[4*k4+1] + w.z * h[4*k4+2] + w.w * h[4*k4+3];
    }
    dec[b * A_ + a] = acc;
  }
}

// ---------------------------------------------------------------------------
// K2 (MFMA): scores[m] += sum_a relu(feat[m,:]·Wenc[a,:] + dec[b,a]) * wcom[a]
//   A = feat fp32 -> REG-STAGED -> f16 LDS (cvt_pkrtz once at stage).
//   B = Wenc f16 via global_load_lds. 128x128 tile, BK=64.
//   LDS: As 16KB + Bs 16KB + decS 1KB = 33.5KB.
//   Reg-staging enables race-free prefetch with SINGLE-buffered LDS:
//   A-loads for kt+64 are issued between the barriers -> latency hides
//   under the MFMA phase (T14). f16 A halves ds_read traffic (24->16
//   wave-b128/K-step) and kills the 32 inner-loop cvt per wave-step.
//   Swizzle (both As and Bs, 8 granules/row): slot = g ^ (row&7).
//   Conflict-free on read (8-lane b128 phase covers 8 distinct slots)
//   and on write (4 rows x 2 halves per phase -> 8 distinct slots).
//   1-D grid, XCD-aware decode: 4 a-blocks of one m-tile land on one XCD.
// ---------------------------------------------------------------------------
__global__ __launch_bounds__(256) void k_scores_mfma(const float* __restrict__ fA,
                                                     const _Float16* __restrict__ fB,
                                                     const float* __restrict__ dec,
                                                     const float* __restrict__ wcom,
                                                     float* __restrict__ scores) {
  __shared__ _Float16  As[128 * 64];   // f16, 128 B/row = 8 granules
  __shared__ _Float16  Bs[128 * 64];   // f16, 128 B/row = 8 granules
  __shared__ float decS[2][128];

  const int tid  = threadIdx.x;
  const int lane = tid & 63;
  const int w    = tid >> 6;

  // XCD-aware (m-tile, a-tile) decode from 1-D block id.
  const int l = blockIdx.x;
  int at_, mt;
  if (l < 768) { at_ = (l >> 3) & 3; mt = (l >> 5) * 8 + (l & 7); }
  else { const int idx = l - 768; at_ = idx >> 2; mt = 192 + (idx & 3); }
  const int a0 = at_ * 128;
  const int m0 = mt * 128;

  const int wm   = w & 1;
  const int wn   = w >> 1;
  const int quad = lane >> 4;
  const int l16  = lane & 15;

  f32x4 acc[4][4];
#pragma unroll
  for (int i = 0; i < 4; i++)
#pragma unroll
    for (int j = 0; j < 4; j++)
#pragma unroll
      for (int k = 0; k < 4; k++) acc[i][j][k] = 0.f;

  // epilogue dec rows (visibility covered by K-loop barriers)
  const int b0 = m0 / L_;
  {
    const int i = tid >> 7;
    const int j = tid & 127;
    int bb = b0 + i; if (bb > B_ - 1) bb = B_ - 1;
    decS[i][j] = dec[bb * A_ + a0 + j];
  }

  // A reg-staging: thread -> (row = tid>>1, half = tid&1), 32 floats = 8 float4.
  const int arow = tid >> 1;
  const int ah   = tid & 1;
  const int ar7  = arow & 7;
  const float* aP = fA + (size_t)(m0 + arow) * F_ + ah * 32;
  // B staging via global_load_lds: 4 issues, 8 rows x 8 granule-slots each,
  // slot(lane&7) holds global granule (lane&7)^srowB; row&7 == srowB.
  const int srowB = lane >> 3;             // 0..7
  const _Float16* pB = fB + (size_t)(a0 + w * 32 + srowB) * F_
                          + (size_t)(((lane & 7) ^ srowB) * 8);

  // prologue: load A tile kt=0 into regs
  float4 fr[8];
#pragma unroll
  for (int jj = 0; jj < 8; jj++) fr[jj] = *(const float4*)(aP + jj * 4);

  for (int kt = 0; kt < F_; kt += 64) {
    // B async loads for this tile (fly under the cvt/ds_write below)
#pragma unroll
    for (int i = 0; i < 4; i++)
      gld_lds16(pB + (size_t)(i * 8) * F_ + kt, &Bs[(w * 32 + i * 8) * 64]);

    // cvt + swizzled ds_write of A tile (regs already hold tile kt)
#pragma unroll
    for (int j = 0; j < 4; j++) {
      union { half8 v; half2v h2[4]; } u;
      u.h2[0] = (half2v)__builtin_amdgcn_cvt_pkrtz(fr[2*j].x,   fr[2*j].y);
      u.h2[1] = (half2v)__builtin_amdgcn_cvt_pkrtz(fr[2*j].z,   fr[2*j].w);
      u.h2[2] = (half2v)__builtin_amdgcn_cvt_pkrtz(fr[2*j+1].x, fr[2*j+1].y);
      u.h2[3] = (half2v)__builtin_amdgcn_cvt_pkrtz(fr[2*j+1].z, fr[2*j+1].w);
      *(half8*)&As[arow * 64 + (((ah << 2) | j) ^ ar7) * 8] = u.v;
    }
    __syncthreads();   // As writes + Bs gld_lds drained

    // prefetch next A tile into regs — latency hides under MFMA phase
    if (kt + 64 < F_) {
#pragma unroll
      for (int jj = 0; jj < 8; jj++)
        fr[jj] = *(const float4*)(aP + kt + 64 + jj * 4);
    }

#pragma unroll
    for (int kk = 0; kk < 2; kk++) {
      half8 af[4], bf[4];
#pragma unroll
      for (int mf = 0; mf < 4; mf++) {
        const int row = wm * 64 + mf * 16 + l16;
        af[mf] = *(const half8*)&As[row * 64 + ((((kk << 2) | quad)) ^ (row & 7)) * 8];
      }
#pragma unroll
      for (int at = 0; at < 4; at++) {
        const int row = wn * 64 + at * 16 + l16;
        bf[at] = *(const half8*)&Bs[row * 64 + ((((kk << 2) | quad)) ^ (row & 7)) * 8];
      }
#pragma unroll
      for (int mf = 0; mf < 4; mf++)
#pragma unroll
        for (int at = 0; at < 4; at++)
          acc[mf][at] = __builtin_amdgcn_mfma_f32_16x16x32_f16(af[mf], bf[at], acc[mf][at], 0, 0, 0);
    }
    __syncthreads();   // protect As/Bs overwrite next iteration
  }

  float w4[4];
#pragma unroll
  for (int at = 0; at < 4; at++) w4[at] = wcom[a0 + wn * 64 + at * 16 + l16];

#pragma unroll
  for (int mf = 0; mf < 4; mf++) {
#pragma unroll
    for (int r = 0; r < 4; r++) {
      const int m  = m0 + wm * 64 + mf * 16 + quad * 4 + r;  // C/D: row=(lane>>4)*4+reg
      const int db = m / L_ - b0;
      float p = 0.f;
#pragma unroll
      for (int at = 0; at < 4; at++) {
        const float e = acc[mf][at][r] + decS[db][wn * 64 + at * 16 + l16];
        p = fmaf(fmaxf(e, 0.f), w4[at], p);
      }
      p += __shfl_xor(p, 1);
      p += __shfl_xor(p, 2);
      p += __shfl_xor(p, 4);
      p += __shfl_xor(p, 8);
      if (l16 == 0) atomicAdd(&scores[m], p);
    }
  }
}

// ---------------------------------------------------------------------------
// K_softmax: alpha[b,:] = softmax(scores[b,:]). 128 blocks x 256 thr, ~2us.
// ---------------------------------------------------------------------------
__global__ __launch_bounds__(256) void k_softmax(const float* __restrict__ scores,
                                                 float* __restrict__ alpha) {
  const int b = blockIdx.x, t = threadIdx.x;
  __shared__ float redm[4];
  __shared__ float reds[4];

  float s = (t < L_) ? scores[b * L_ + t] : -INFINITY;
  float m = s;
#pragma unroll
  for (int o = 32; o >= 1; o >>= 1) m = fmaxf(m, __shfl_xor(m, o));
  if ((t & 63) == 0) redm[t >> 6] = m;
  __syncthreads();
  m = fmaxf(fmaxf(redm[0], redm[1]), fmaxf(redm[2], redm[3]));
  float e = (t < L_) ? expf(s - m) : 0.f;
  float sum = e;
#pragma unroll
  for (int o = 32; o >= 1; o >>= 1) sum += __shfl_xor(sum, o);
  if ((t & 63) == 0) reds[t >> 6] = sum;
  __syncthreads();
  sum = reds[0] + reds[1] + reds[2] + reds[3];
  if (t < L_) alpha[b * L_ + t] = e / sum;
}

// ---------------------------------------------------------------------------
// K_attn: pure weighted sum over fp32 feat, reading precomputed alpha.
// grid (8 f-chunks, B) x 128 threads = 8 waves/CU; two independent row
// streams (ll, ll+98) x unroll 7 -> ~14 loads in flight per thread.
// ---------------------------------------------------------------------------
__global__ __launch_bounds__(128) void k_attn_f32(const float* __restrict__ feat,
                                                  const float* __restrict__ alpha,
                                                  float* __restrict__ out) {
  const int fc = blockIdx.x, b = blockIdx.y, t = threadIdx.x;
  __shared__ float al[L_];

  al[t] = alpha[b * L_ + t];
  if (t < L_ - 128) al[t + 128] = alpha[b * L_ + t + 128];
  __syncthreads();

  const int f0 = fc * 256 + t * 2;
  const float2* fp = (const float2*)(feat + (size_t)b * L_ * F_ + f0);
  float a0x = 0.f, a0y = 0.f, a1x = 0.f, a1y = 0.f;
#pragma unroll 7
  for (int ll = 0; ll < 98; ll++) {
    const float2 v0 = fp[(size_t)ll * (F_ / 2)];
    const float2 v1 = fp[(size_t)(ll + 98) * (F_ / 2)];
    const float w0 = al[ll];
    const float w1 = al[ll + 98];
    a0x = fmaf(v0.x, w0, a0x);
    a0y = fmaf(v0.y, w0, a0y);
    a1x = fmaf(v1.x, w1, a1x);
    a1y = fmaf(v1.y, w1, a1y);
  }
  float2 o = { a0x + a1x, a0y + a1y };
  *(float2*)(out + (size_t)b * F_ + f0) = o;
}

// ---------------------------------------------------------------------------
// Fallback fp32 GEMM path (ws too small — effectively never taken)
// ---------------------------------------------------------------------------
__global__ __launch_bounds__(256) void k_scores_f32(const float* __restrict__ feat,
                                                    const float* __restrict__ Wenc,
                                                    const float* __restrict__ dec,
                                                    const float* __restrict__ wcom,
                                                    float* __restrict__ scores) {
  __shared__ float As[16][128];
  __shared__ float Bs[16][128];
  const int tid = threadIdx.x;
  const int m0 = blockIdx.x * 128;
  const int a0 = blockIdx.y * 128;
  const int tx = tid & 15;
  const int ty = tid >> 4;
  float acc[8][8];
#pragma unroll
  for (int i = 0; i < 8; i++)
#pragma unroll
    for (int j = 0; j < 8; j++) acc[i][j] = 0.f;
  for (int kt = 0; kt < F_; kt += 16) {
#pragma unroll
    for (int rep = 0; rep < 2; rep++) {
      const int idx = rep * 256 + tid;
      const int row = idx >> 2;
      const int kp  = (idx & 3) << 2;
      const float4 v = *(const float4*)(feat + (size_t)(m0 + row) * F_ + kt + kp);
      As[kp+0][row] = v.x; As[kp+1][row] = v.y; As[kp+2][row] = v.z; As[kp+3][row] = v.w;
      const float4 w = *(const float4*)(Wenc + (size_t)(a0 + row) * F_ + kt + kp);
      Bs[kp+0][row] = w.x; Bs[kp+1][row] = w.y; Bs[kp+2][row] = w.z; Bs[kp+3][row] = w.w;
    }
    __syncthreads();
#pragma unroll
    for (int k = 0; k < 16; k++) {
      float ar[8], br[8];
      *(float4*)&ar[0] = *(const float4*)&As[k][ty * 8];
      *(float4*)&ar[4] = *(const float4*)&As[k][ty * 8 + 4];
      *(float4*)&br[0] = *(const float4*)&Bs[k][tx * 8];
      *(float4*)&br[4] = *(const float4*)&Bs[k][tx * 8 + 4];
#pragma unroll
      for (int i = 0; i < 8; i++)
#pragma unroll
        for (int j = 0; j < 8; j++) acc[i][j] = fmaf(ar[i], br[j], acc[i][j]);
    }
    __syncthreads();
  }
  float w8[8];
  *(float4*)&w8[0] = *(const float4*)(wcom + a0 + tx * 8);
  *(float4*)&w8[4] = *(const float4*)(wcom + a0 + tx * 8 + 4);
#pragma unroll
  for (int i = 0; i < 8; i++) {
    const int m = m0 + ty * 8 + i;
    const int b = m / L_;
    const float* dp = dec + b * A_ + a0 + tx * 8;
    float p = 0.f;
#pragma unroll
    for (int j = 0; j < 8; j++) {
      const float e = acc[i][j] + dp[j];
      p = fmaf(fmaxf(e, 0.f), w8[j], p);
    }
    p += __shfl_xor(p, 1);
    p += __shfl_xor(p, 2);
    p += __shfl_xor(p, 4);
    p += __shfl_xor(p, 8);
    if (tx == 0) atomicAdd(&scores[m], p);
  }
}

__global__ __launch_bounds__(256) void k_dec_only(const float* __restrict__ hs,
                                                  const float* __restrict__ Wdec,
                                                  const float* __restrict__ bdec,
                                                  const float* __restrict__ benc,
                                                  float* __restrict__ dec,
                                                  float* __restrict__ scores) {
  const int b = blockIdx.x, t = threadIdx.x;
  const int g = b * 256 + t;
  if (g < ML_) scores[g] = 0.f;
  __shared__ float h[H_];
  h[t]       = hs[b * H_ + t];
  h[t + 256] = hs[b * H_ + t + 256];
  __syncthreads();
#pragma unroll
  for (int r = 0; r < 2; r++) {
    const int a = t + r * 256;
    float acc = bdec[a] + benc[a];
    const float4* wr = (const float4*)(Wdec + (size_t)a * H_);
#pragma unroll 4
    for (int k4 = 0; k4 < H_ / 4; k4++) {
      const float4 w = wr[k4];
      acc += w.x * h[4*k4] + w.y * h[4*k4+1] + w.z * h[4*k4+2] + w.w * h[4*k4+3];
    }
    dec[b * A_ + a] = acc;
  }
}

// ---------------------------------------------------------------------------
extern "C" void kernel_launch(void* const* d_in, const int* in_sizes, int n_in,
                              void* d_out, int out_size, void* d_ws, size_t ws_size,
                              hipStream_t stream) {
  const float* feat = (const float*)d_in[0];   // [B,L,F]
  const float* hs   = (const float*)d_in[1];   // [B,H]
  const float* Wenc = (const float*)d_in[2];   // [A,F]
  const float* benc = (const float*)d_in[3];   // [A]
  const float* Wdec = (const float*)d_in[4];   // [A,H]
  const float* bdec = (const float*)d_in[5];   // [A]
  const float* wcom = (const float*)d_in[6];   // [1,A]
  // d_in[7] = b_com: softmax-invariant, unused

  float* out   = (float*)d_out;                // [B*F] weighted ++ [B*L] alpha
  float* alpha = out + B_ * F_;
  float* dec    = (float*)d_ws;                // [B*A]
  float* scores = dec + B_ * A_;               // [B*L]

  const size_t need = (size_t)(B_ * A_ + ML_) * 4 + (size_t)A_ * F_ * 2;

  if (ws_size >= need) {
    _Float16* wH = (_Float16*)(scores + ML_);  // [A_, F_] f16
    k_prep<<<dim3(128), dim3(256), 0, stream>>>(
        (const float4*)Wenc, (half4v*)wH, hs, Wdec, bdec, benc, dec, scores);
    k_scores_mfma<<<dim3(784), dim3(256), 0, stream>>>(feat, wH, dec, wcom, scores);
  } else {
    k_dec_only<<<dim3(B_), dim3(256), 0, stream>>>(hs, Wdec, bdec, benc, dec, scores);
    k_scores_f32<<<dim3(ML_ / 128, A_ / 128), dim3(256), 0, stream>>>(feat, Wenc, dec, wcom, scores);
  }
  k_softmax<<<dim3(B_), dim3(256), 0, stream>>>(scores, alpha);
  k_attn_f32<<<dim3(8, B_), dim3(128), 0, stream>>>(feat, alpha, out);
}

// Round 4
// 466.977 us; speedup vs baseline: 1.0109x; 1.0109x over previous
//
#include <hip/hip_runtime.h>
#include <hip/hip_bf16.h>
#include <math.h>

#define B_  128
#define L_  196
#define F_  2048
#define H_  512
#define A_  512
#define ML_ (B_*L_)   // 25088 rows = 196 tiles of 128 exactly

typedef _Float16 half8 __attribute__((ext_vector_type(8)));
typedef _Float16 half4v __attribute__((ext_vector_type(4)));
typedef _Float16 half2v __attribute__((ext_vector_type(2)));
typedef float f32x4 __attribute__((ext_vector_type(4)));

// async 16B global->LDS (LDS dest = wave-uniform base + lane*16)
__device__ __forceinline__ void gld_lds16(const void* g, void* l) {
  __builtin_amdgcn_global_load_lds((const __attribute__((address_space(1))) void*)g,
                                   (__attribute__((address_space(3))) void*)l, 16, 0, 0);
}

// ---------------------------------------------------------------------------
// K_prep (small): 128 blocks. Wenc fp32->f16 (4 MB, 8-deep unrolled),
// dec[b][a] = b_dec+b_enc+hs·Wdec^T, zero scores.
// ---------------------------------------------------------------------------
__global__ __launch_bounds__(256) void k_prep(const float4* __restrict__ Wenc4,
                                              half4v* __restrict__ wH,
                                              const float* __restrict__ hs,
                                              const float* __restrict__ Wdec,
                                              const float* __restrict__ bdec,
                                              const float* __restrict__ benc,
                                              float* __restrict__ dec,
                                              float* __restrict__ scores) {
  const int b = blockIdx.x, t = threadIdx.x;

  {
    const int base = b * 2048 + t;
    float4 v[8];
#pragma unroll
    for (int j = 0; j < 8; j++) v[j] = Wenc4[base + j * 256];
#pragma unroll
    for (int j = 0; j < 8; j++) {
      half4v o = { (_Float16)v[j].x, (_Float16)v[j].y, (_Float16)v[j].z, (_Float16)v[j].w };
      wH[base + j * 256] = o;
    }
  }

  const int g = b * 256 + t;
  if (g < ML_) scores[g] = 0.f;

  __shared__ float h[H_];
  h[t]       = hs[b * H_ + t];
  h[t + 256] = hs[b * H_ + t + 256];
  __syncthreads();

#pragma unroll
  for (int r = 0; r < 2; r++) {
    const int a = t + r * 256;
    float acc = bdec[a] + benc[a];
    const float4* wr = (const float4*)(Wdec + (size_t)a * H_);
#pragma unroll 4
    for (int k4 = 0; k4 < H_ / 4; k4++) {
      const float4 w = wr[k4];
      acc += w.x * h[4*k4] + w.y * h[4*k4+1] + w.z * h[4*k4+2] + w.w * h[4*k4+3];
    }
    dec[b * A_ + a] = acc;
  }
}

// ---------------------------------------------------------------------------
// K2 (MFMA): scores[m] += sum_a relu(feat[m,:]·Wenc[a,:] + dec[b,a]) * wcom[a]
//   R4: T3+T4 2-phase pipeline. BK=32 ping-pong double buffer, all staging
//   via global_load_lds (coalesced 1KB/issue, async). Counted s_waitcnt
//   vmcnt(6): each step's 6 loads/wave stay in flight across the raw
//   s_barrier (no full drain — the m97-ceiling stall). Exactly 6 VMEM ops
//   per wave per step -> count is exact. A stays fp32 in LDS (pkrtz at
//   frag-load): keeps gld_lds coalescing, cvt hides in MFMA phase.
//   LDS: As 2x16KB + Bs 2x8KB + decS 1KB = 49.25KB -> 3 blocks/CU.
//   A swizzle (8 granules/row):  slot = g ^ (row&7)  [conflict-free]
//   B swizzle (4 granules/row):  slot = g ^ (row&3)  [2-way = free, m136]
//   Same involution on pre-swizzled global source and LDS read (rule #21).
//   1-D grid, XCD-aware decode: 4 a-blocks of one m-tile land on one XCD.
// ---------------------------------------------------------------------------
__global__ __launch_bounds__(256) void k_scores_mfma(const float* __restrict__ fA,
                                                     const _Float16* __restrict__ fB,
                                                     const float* __restrict__ dec,
                                                     const float* __restrict__ wcom,
                                                     float* __restrict__ scores) {
  __shared__ float     As[2][128 * 32];   // fp32, 128 B/row = 8 granules
  __shared__ _Float16  Bs[2][128 * 32];   // f16,   64 B/row = 4 granules
  __shared__ float decS[2][128];

  const int tid  = threadIdx.x;
  const int lane = tid & 63;
  const int w    = tid >> 6;

  // XCD-aware (m-tile, a-tile) decode from 1-D block id.
  const int l = blockIdx.x;
  int at_, mt;
  if (l < 768) { at_ = (l >> 3) & 3; mt = (l >> 5) * 8 + (l & 7); }
  else { const int idx = l - 768; at_ = idx >> 2; mt = 192 + (idx & 3); }
  const int a0 = at_ * 128;
  const int m0 = mt * 128;

  const int wm   = w & 1;
  const int wn   = w >> 1;
  const int quad = lane >> 4;
  const int l16  = lane & 15;

  f32x4 acc[4][4];
#pragma unroll
  for (int i = 0; i < 4; i++)
#pragma unroll
    for (int j = 0; j < 4; j++)
#pragma unroll
      for (int k = 0; k < 4; k++) acc[i][j][k] = 0.f;

  // epilogue dec rows (before any gld_lds issues so its waitcnt is isolated;
  // cross-thread visibility covered by the K-loop barriers)
  const int b0 = m0 / L_;
  {
    const int i = tid >> 7;
    const int j = tid & 127;
    int bb = b0 + i; if (bb > B_ - 1) bb = B_ - 1;
    decS[i][j] = dec[bb * A_ + a0 + j];
  }

  // A staging: 4 issues/wave/step; issue i = 8 rows x 8 granule-slots.
  // lane -> (srowA = lane>>3, slot = lane&7); fetches granule slot^srowA;
  // row&7 == srowA  (w*32, i*8 are multiples of 8).
  const int srowA = lane >> 3;             // 0..7
  const float* pA = fA + (size_t)(m0 + w * 32 + srowA) * F_
                       + (size_t)(((lane & 7) ^ srowA) * 4);
  // B staging: 2 issues/wave/step; issue i = 16 rows x 4 granule-slots.
  // lane -> (srowB = lane>>2, slot = lane&3); fetches granule slot^(srowB&3);
  // row&3 == srowB&3.
  const int srowB = lane >> 2;             // 0..15
  const _Float16* pB = fB + (size_t)(a0 + w * 32 + srowB) * F_
                          + (size_t)(((lane & 3) ^ (srowB & 3)) * 8);

  // prologue: issue step-0 loads into buffer 0
#pragma unroll
  for (int i = 0; i < 4; i++)
    gld_lds16(pA + (size_t)(i * 8) * F_, &As[0][(w * 32 + i * 8) * 32]);
#pragma unroll
  for (int i = 0; i < 2; i++)
    gld_lds16(pB + (size_t)(i * 16) * F_, &Bs[0][(w * 32 + i * 16) * 32]);

  // one K-step: data for this step is ready-in-flight in As/Bs[buf];
  // prefetch step `spre` into buf^1, wait own 6 step loads, barrier, compute.
  auto kstep = [&](int buf, int spre) {
#pragma unroll
    for (int i = 0; i < 4; i++)
      gld_lds16(pA + (size_t)(i * 8) * F_ + spre * 32,
                &As[buf ^ 1][(w * 32 + i * 8) * 32]);
#pragma unroll
    for (int i = 0; i < 2; i++)
      gld_lds16(pB + (size_t)(i * 16) * F_ + spre * 32,
                &Bs[buf ^ 1][(w * 32 + i * 16) * 32]);
    // wait this step's 6 loads (the 6 just-issued prefetches stay in flight)
    asm volatile("s_waitcnt vmcnt(6)" ::: "memory");
    __builtin_amdgcn_s_barrier();
    __builtin_amdgcn_sched_barrier(0);

    half8 af[4], bf[4];
#pragma unroll
    for (int mf = 0; mf < 4; mf++) {
      const int row = wm * 64 + mf * 16 + l16;
      const int s0  = (quad * 2) ^ (row & 7);
      const float4 f0 = *(const float4*)&As[buf][row * 32 + s0 * 4];
      const float4 f1 = *(const float4*)&As[buf][row * 32 + (s0 ^ 1) * 4];
      union { half8 v; half2v h2[4]; } u;
      u.h2[0] = (half2v)__builtin_amdgcn_cvt_pkrtz(f0.x, f0.y);
      u.h2[1] = (half2v)__builtin_amdgcn_cvt_pkrtz(f0.z, f0.w);
      u.h2[2] = (half2v)__builtin_amdgcn_cvt_pkrtz(f1.x, f1.y);
      u.h2[3] = (half2v)__builtin_amdgcn_cvt_pkrtz(f1.z, f1.w);
      af[mf] = u.v;
    }
#pragma unroll
    for (int at = 0; at < 4; at++) {
      const int row = wn * 64 + at * 16 + l16;
      const int sb  = quad ^ (row & 3);
      bf[at] = *(const half8*)&Bs[buf][row * 32 + sb * 8];
    }
#pragma unroll
    for (int mf = 0; mf < 4; mf++)
#pragma unroll
      for (int at = 0; at < 4; at++)
        acc[mf][at] = __builtin_amdgcn_mfma_f32_16x16x32_f16(af[mf], bf[at], acc[mf][at], 0, 0, 0);

    __builtin_amdgcn_sched_barrier(0);
    __builtin_amdgcn_s_barrier();   // all waves done reading buf -> next
    __builtin_amdgcn_sched_barrier(0);  // issues into buf stay below
  };

  for (int s = 0; s < 64; s += 2) {
    kstep(0, s + 1);                       // compute s   (buf0), prefetch s+1
    kstep(1, s + 2 < 64 ? s + 2 : 63);     // compute s+1 (buf1), prefetch s+2
  }
  // tail clamp re-issues step 63 into buf0 (never read) - 6 wasted loads/wave.

  float w4[4];
#pragma unroll
  for (int at = 0; at < 4; at++) w4[at] = wcom[a0 + wn * 64 + at * 16 + l16];

#pragma unroll
  for (int mf = 0; mf < 4; mf++) {
#pragma unroll
    for (int r = 0; r < 4; r++) {
      const int m  = m0 + wm * 64 + mf * 16 + quad * 4 + r;  // C/D: row=(lane>>4)*4+reg
      const int db = m / L_ - b0;
      float p = 0.f;
#pragma unroll
      for (int at = 0; at < 4; at++) {
        const float e = acc[mf][at][r] + decS[db][wn * 64 + at * 16 + l16];
        p = fmaf(fmaxf(e, 0.f), w4[at], p);
      }
      p += __shfl_xor(p, 1);
      p += __shfl_xor(p, 2);
      p += __shfl_xor(p, 4);
      p += __shfl_xor(p, 8);
      if (l16 == 0) atomicAdd(&scores[m], p);
    }
  }
}

// ---------------------------------------------------------------------------
// K_softmax: alpha[b,:] = softmax(scores[b,:]). 128 blocks x 256 thr, ~2us.
// ---------------------------------------------------------------------------
__global__ __launch_bounds__(256) void k_softmax(const float* __restrict__ scores,
                                                 float* __restrict__ alpha) {
  const int b = blockIdx.x, t = threadIdx.x;
  __shared__ float redm[4];
  __shared__ float reds[4];

  float s = (t < L_) ? scores[b * L_ + t] : -INFINITY;
  float m = s;
#pragma unroll
  for (int o = 32; o >= 1; o >>= 1) m = fmaxf(m, __shfl_xor(m, o));
  if ((t & 63) == 0) redm[t >> 6] = m;
  __syncthreads();
  m = fmaxf(fmaxf(redm[0], redm[1]), fmaxf(redm[2], redm[3]));
  float e = (t < L_) ? expf(s - m) : 0.f;
  float sum = e;
#pragma unroll
  for (int o = 32; o >= 1; o >>= 1) sum += __shfl_xor(sum, o);
  if ((t & 63) == 0) reds[t >> 6] = sum;
  __syncthreads();
  sum = reds[0] + reds[1] + reds[2] + reds[3];
  if (t < L_) alpha[b * L_ + t] = e / sum;
}

// ---------------------------------------------------------------------------
// K_attn: pure weighted sum over fp32 feat, reading precomputed alpha.
// grid (8 f-chunks, B) x 128 threads; two independent row streams.
// ---------------------------------------------------------------------------
__global__ __launch_bounds__(128) void k_attn_f32(const float* __restrict__ feat,
                                                  const float* __restrict__ alpha,
                                                  float* __restrict__ out) {
  const int fc = blockIdx.x, b = blockIdx.y, t = threadIdx.x;
  __shared__ float al[L_];

  al[t] = alpha[b * L_ + t];
  if (t < L_ - 128) al[t + 128] = alpha[b * L_ + t + 128];
  __syncthreads();

  const int f0 = fc * 256 + t * 2;
  const float2* fp = (const float2*)(feat + (size_t)b * L_ * F_ + f0);
  float a0x = 0.f, a0y = 0.f, a1x = 0.f, a1y = 0.f;
#pragma unroll 7
  for (int ll = 0; ll < 98; ll++) {
    const float2 v0 = fp[(size_t)ll * (F_ / 2)];
    const float2 v1 = fp[(size_t)(ll + 98) * (F_ / 2)];
    const float w0 = al[ll];
    const float w1 = al[ll + 98];
    a0x = fmaf(v0.x, w0, a0x);
    a0y = fmaf(v0.y, w0, a0y);
    a1x = fmaf(v1.x, w1, a1x);
    a1y = fmaf(v1.y, w1, a1y);
  }
  float2 o = { a0x + a1x, a0y + a1y };
  *(float2*)(out + (size_t)b * F_ + f0) = o;
}

// ---------------------------------------------------------------------------
// Fallback fp32 GEMM path (ws too small — effectively never taken)
// ---------------------------------------------------------------------------
__global__ __launch_bounds__(256) void k_scores_f32(const float* __restrict__ feat,
                                                    const float* __restrict__ Wenc,
                                                    const float* __restrict__ dec,
                                                    const float* __restrict__ wcom,
                                                    float* __restrict__ scores) {
  __shared__ float As[16][128];
  __shared__ float Bs[16][128];
  const int tid = threadIdx.x;
  const int m0 = blockIdx.x * 128;
  const int a0 = blockIdx.y * 128;
  const int tx = tid & 15;
  const int ty = tid >> 4;
  float acc[8][8];
#pragma unroll
  for (int i = 0; i < 8; i++)
#pragma unroll
    for (int j = 0; j < 8; j++) acc[i][j] = 0.f;
  for (int kt = 0; kt < F_; kt += 16) {
#pragma unroll
    for (int rep = 0; rep < 2; rep++) {
      const int idx = rep * 256 + tid;
      const int row = idx >> 2;
      const int kp  = (idx & 3) << 2;
      const float4 v = *(const float4*)(feat + (size_t)(m0 + row) * F_ + kt + kp);
      As[kp+0][row] = v.x; As[kp+1][row] = v.y; As[kp+2][row] = v.z; As[kp+3][row] = v.w;
      const float4 w = *(const float4*)(Wenc + (size_t)(a0 + row) * F_ + kt + kp);
      Bs[kp+0][row] = w.x; Bs[kp+1][row] = w.y; Bs[kp+2][row] = w.z; Bs[kp+3][row] = w.w;
    }
    __syncthreads();
#pragma unroll
    for (int k = 0; k < 16; k++) {
      float ar[8], br[8];
      *(float4*)&ar[0] = *(const float4*)&As[k][ty * 8];
      *(float4*)&ar[4] = *(const float4*)&As[k][ty * 8 + 4];
      *(float4*)&br[0] = *(const float4*)&Bs[k][tx * 8];
      *(float4*)&br[4] = *(const float4*)&Bs[k][tx * 8 + 4];
#pragma unroll
      for (int i = 0; i < 8; i++)
#pragma unroll
        for (int j = 0; j < 8; j++) acc[i][j] = fmaf(ar[i], br[j], acc[i][j]);
    }
    __syncthreads();
  }
  float w8[8];
  *(float4*)&w8[0] = *(const float4*)(wcom + a0 + tx * 8);
  *(float4*)&w8[4] = *(const float4*)(wcom + a0 + tx * 8 + 4);
#pragma unroll
  for (int i = 0; i < 8; i++) {
    const int m = m0 + ty * 8 + i;
    const int b = m / L_;
    const float* dp = dec + b * A_ + a0 + tx * 8;
    float p = 0.f;
#pragma unroll
    for (int j = 0; j < 8; j++) {
      const float e = acc[i][j] + dp[j];
      p = fmaf(fmaxf(e, 0.f), w8[j], p);
    }
    p += __shfl_xor(p, 1);
    p += __shfl_xor(p, 2);
    p += __shfl_xor(p, 4);
    p += __shfl_xor(p, 8);
    if (tx == 0) atomicAdd(&scores[m], p);
  }
}

__global__ __launch_bounds__(256) void k_dec_only(const float* __restrict__ hs,
                                                  const float* __restrict__ Wdec,
                                                  const float* __restrict__ bdec,
                                                  const float* __restrict__ benc,
                                                  float* __restrict__ dec,
                                                  float* __restrict__ scores) {
  const int b = blockIdx.x, t = threadIdx.x;
  const int g = b * 256 + t;
  if (g < ML_) scores[g] = 0.f;
  __shared__ float h[H_];
  h[t]       = hs[b * H_ + t];
  h[t + 256] = hs[b * H_ + t + 256];
  __syncthreads();
#pragma unroll
  for (int r = 0; r < 2; r++) {
    const int a = t + r * 256;
    float acc = bdec[a] + benc[a];
    const float4* wr = (const float4*)(Wdec + (size_t)a * H_);
#pragma unroll 4
    for (int k4 = 0; k4 < H_ / 4; k4++) {
      const float4 w = wr[k4];
      acc += w.x * h[4*k4] + w.y * h[4*k4+1] + w.z * h[4*k4+2] + w.w * h[4*k4+3];
    }
    dec[b * A_ + a] = acc;
  }
}

// ---------------------------------------------------------------------------
extern "C" void kernel_launch(void* const* d_in, const int* in_sizes, int n_in,
                              void* d_out, int out_size, void* d_ws, size_t ws_size,
                              hipStream_t stream) {
  const float* feat = (const float*)d_in[0];   // [B,L,F]
  const float* hs   = (const float*)d_in[1];   // [B,H]
  const float* Wenc = (const float*)d_in[2];   // [A,F]
  const float* benc = (const float*)d_in[3];   // [A]
  const float* Wdec = (const float*)d_in[4];   // [A,H]
  const float* bdec = (const float*)d_in[5];   // [A]
  const float* wcom = (const float*)d_in[6];   // [1,A]
  // d_in[7] = b_com: softmax-invariant, unused

  float* out   = (float*)d_out;                // [B*F] weighted ++ [B*L] alpha
  float* alpha = out + B_ * F_;
  float* dec    = (float*)d_ws;                // [B*A]
  float* scores = dec + B_ * A_;               // [B*L]

  const size_t need = (size_t)(B_ * A_ + ML_) * 4 + (size_t)A_ * F_ * 2;

  if (ws_size >= need) {
    _Float16* wH = (_Float16*)(scores + ML_);  // [A_, F_] f16
    k_prep<<<dim3(128), dim3(256), 0, stream>>>(
        (const float4*)Wenc, (half4v*)wH, hs, Wdec, bdec, benc, dec, scores);
    k_scores_mfma<<<dim3(784), dim3(256), 0, stream>>>(feat, wH, dec, wcom, scores);
  } else {
    k_dec_only<<<dim3(B_), dim3(256), 0, stream>>>(hs, Wdec, bdec, benc, dec, scores);
    k_scores_f32<<<dim3(ML_ / 128, A_ / 128), dim3(256), 0, stream>>>(feat, Wenc, dec, wcom, scores);
  }
  k_softmax<<<dim3(B_), dim3(256), 0, stream>>>(scores, alpha);
  k_attn_f32<<<dim3(8, B_), dim3(128), 0, stream>>>(feat, alpha, out);
}

// Round 6
// 428.136 us; speedup vs baseline: 1.1026x; 1.0907x over previous
//
#include <hip/hip_runtime.h>
#include <hip/hip_bf16.h>
#include <math.h>

#define B_  128
#define L_  196
#define F_  2048
#define H_  512
#define A_  512
#define ML_ (B_*L_)   // 25088 rows = 196 tiles of 128 exactly

typedef _Float16 half8 __attribute__((ext_vector_type(8)));
typedef _Float16 half4v __attribute__((ext_vector_type(4)));
typedef _Float16 half2v __attribute__((ext_vector_type(2)));
typedef float f32x4 __attribute__((ext_vector_type(4)));

// async 16B global->LDS (LDS dest = wave-uniform base + lane*16)
__device__ __forceinline__ void gld_lds16(const void* g, void* l) {
  __builtin_amdgcn_global_load_lds((const __attribute__((address_space(1))) void*)g,
                                   (__attribute__((address_space(3))) void*)l, 16, 0, 0);
}

// ---------------------------------------------------------------------------
// K_prep (small): 128 blocks. Wenc fp32->f16 (4 MB, 8-deep unrolled),
// dec[b][a] = b_dec+b_enc+hs·Wdec^T, zero scores.
// ---------------------------------------------------------------------------
__global__ __launch_bounds__(256) void k_prep(const float4* __restrict__ Wenc4,
                                              half4v* __restrict__ wH,
                                              const float* __restrict__ hs,
                                              const float* __restrict__ Wdec,
                                              const float* __restrict__ bdec,
                                              const float* __restrict__ benc,
                                              float* __restrict__ dec,
                                              float* __restrict__ scores) {
  const int b = blockIdx.x, t = threadIdx.x;

  {
    const int base = b * 2048 + t;
    float4 v[8];
#pragma unroll
    for (int j = 0; j < 8; j++) v[j] = Wenc4[base + j * 256];
#pragma unroll
    for (int j = 0; j < 8; j++) {
      half4v o = { (_Float16)v[j].x, (_Float16)v[j].y, (_Float16)v[j].z, (_Float16)v[j].w };
      wH[base + j * 256] = o;
    }
  }

  const int g = b * 256 + t;
  if (g < ML_) scores[g] = 0.f;

  __shared__ float h[H_];
  h[t]       = hs[b * H_ + t];
  h[t + 256] = hs[b * H_ + t + 256];
  __syncthreads();

#pragma unroll
  for (int r = 0; r < 2; r++) {
    const int a = t + r * 256;
    float acc = bdec[a] + benc[a];
    const float4* wr = (const float4*)(Wdec + (size_t)a * H_);
#pragma unroll 4
    for (int k4 = 0; k4 < H_ / 4; k4++) {
      const float4 w = wr[k4];
      acc += w.x * h[4*k4] + w.y * h[4*k4+1] + w.z * h[4*k4+2] + w.w * h[4*k4+3];
    }
    dec[b * A_ + a] = acc;
  }
}

// ---------------------------------------------------------------------------
// K2 (MFMA): scores[m] += sum_a relu(feat[m,:]·Wenc[a,:] + dec[b,a]) * wcom[a]
//   R6 == R5 resubmit (container infra failure, no measurement):
//   BK=64 (32 MFMA/step, R1 cadence), A f16 in LDS via COALESCED
//   reg-staging (wave reads 4x256B row segments per dwordx4; R3's failure
//   was 64x16B scatter), cvt_pkrtz at stage. B double-buffered via
//   global_load_lds + counted vmcnt(12): queue at the wait is
//   [B(s):4, A(s+1):8, B(s+1):4] -> retiring to 12 retires exactly B(s).
//   No vmcnt(0) in the main loop; end-of-step barrier is raw s_barrier
//   (LDS-read retirement implied by MFMA's lgkm waits).
//   LDS: As 16KB + Bs 2x16KB + decS 1KB = 49.25KB -> 3 blocks/CU (grid 784).
//   As swizzle: 16 8B-subgranules/row, slot8 = g8 ^ ((row&7)<<1)
//     write b64: 16-lane phase = one row, 16 distinct slots -> conflict-free
//     read b128: 8-lane phase = 8 rows distinct &7 -> conflict-free
//   Bs swizzle: 8 16B-granules/row, slot = g ^ (row&7), pre-swizzled global
//     source (linear LDS dest, rule #21) -> conflict-free read.
//   1-D grid, XCD-aware decode: 4 a-blocks of one m-tile land on one XCD.
// ---------------------------------------------------------------------------
__global__ __launch_bounds__(256) void k_scores_mfma(const float* __restrict__ fA,
                                                     const _Float16* __restrict__ fB,
                                                     const float* __restrict__ dec,
                                                     const float* __restrict__ wcom,
                                                     float* __restrict__ scores) {
  __shared__ _Float16  As[128 * 64];      // f16, 128 B/row = 8 granules
  __shared__ _Float16  Bs[2][128 * 64];   // f16, 128 B/row = 8 granules
  __shared__ float decS[2][128];

  const int tid  = threadIdx.x;
  const int lane = tid & 63;
  const int w    = tid >> 6;

  // XCD-aware (m-tile, a-tile) decode from 1-D block id.
  const int l = blockIdx.x;
  int at_, mt;
  if (l < 768) { at_ = (l >> 3) & 3; mt = (l >> 5) * 8 + (l & 7); }
  else { const int idx = l - 768; at_ = idx >> 2; mt = 192 + (idx & 3); }
  const int a0 = at_ * 128;
  const int m0 = mt * 128;

  const int wm   = w & 1;
  const int wn   = w >> 1;
  const int quad = lane >> 4;
  const int l16  = lane & 15;

  f32x4 acc[4][4];
#pragma unroll
  for (int i = 0; i < 4; i++)
#pragma unroll
    for (int j = 0; j < 4; j++)
#pragma unroll
      for (int k = 0; k < 4; k++) acc[i][j][k] = 0.f;

  // epilogue dec rows (visibility covered by K-loop barriers)
  const int b0 = m0 / L_;
  {
    const int i = tid >> 7;
    const int j = tid & 127;
    int bb = b0 + i; if (bb > B_ - 1) bb = B_ - 1;
    decS[i][j] = dec[bb * A_ + a0 + j];
  }

  // A staging: chunk i (0..7) covers rows w*32 + i*4 + (lane>>4),
  // cols (lane&15)*4 .. +4  -> 4 coalesced 256B segments per instruction.
  const int arow4 = lane >> 4;           // 0..3
  const int acol  = (lane & 15) * 4;
  const float* pA = fA + (size_t)(m0 + w * 32 + arow4) * F_ + acol;
  const int g8    = lane & 15;           // 8B sub-granule written by this lane

  // B staging via global_load_lds: 4 issues; issue i = rows w*32+i*8+(lane>>3),
  // LDS slot lane&7 holds global granule (lane&7)^(row&7); row&7 == lane>>3.
  const int srowB = lane >> 3;           // 0..7
  const _Float16* pB = fB + (size_t)(a0 + w * 32 + srowB) * F_
                          + (size_t)(((lane & 7) ^ srowB) * 8);

  // prologue: A(0) into regs, B(0) -> Bs[0]
  float4 fr[8];
#pragma unroll
  for (int i = 0; i < 8; i++)
    fr[i] = *(const float4*)(pA + (size_t)(i * 4) * F_);
#pragma unroll
  for (int i = 0; i < 4; i++)
    gld_lds16(pB + (size_t)(i * 8) * F_, &Bs[0][(w * 32 + i * 8) * 64]);

  auto kstep = [&](int kt, int buf, bool last) {
    // cvt + swizzled ds_write of A(s) (fr already holds it; compiler inserts
    // the exact vmcnt wait for fr here, leaving B(s) in flight)
#pragma unroll
    for (int i = 0; i < 8; i++) {
      const int r = w * 32 + i * 4 + arow4;
      half4v h;
      half2v h0 = (half2v)__builtin_amdgcn_cvt_pkrtz(fr[i].x, fr[i].y);
      half2v h1 = (half2v)__builtin_amdgcn_cvt_pkrtz(fr[i].z, fr[i].w);
      h[0] = h0[0]; h[1] = h0[1]; h[2] = h1[0]; h[3] = h1[1];
      *(half4v*)&As[r * 64 + (g8 ^ ((r & 7) << 1)) * 4] = h;
    }
    if (!last) {
      // A(s+1) -> regs (lands under the MFMA phase; consumed at next cvt)
#pragma unroll
      for (int i = 0; i < 8; i++)
        fr[i] = *(const float4*)(pA + (size_t)(i * 4) * F_ + kt + 64);
      // B(s+1) -> other buffer (stays in flight across the barrier)
#pragma unroll
      for (int i = 0; i < 4; i++)
        gld_lds16(pB + (size_t)(i * 8) * F_ + kt + 64,
                  &Bs[buf ^ 1][(w * 32 + i * 8) * 64]);
      // retire exactly B(s) (oldest 4); keep A(s+1)+B(s+1) in flight
      asm volatile("s_waitcnt vmcnt(12) lgkmcnt(0)" ::: "memory");
    } else {
      asm volatile("s_waitcnt vmcnt(0) lgkmcnt(0)" ::: "memory");
    }
    __builtin_amdgcn_s_barrier();
    __builtin_amdgcn_sched_barrier(0);

#pragma unroll
    for (int kk = 0; kk < 2; kk++) {
      half8 af[4], bf[4];
#pragma unroll
      for (int mf = 0; mf < 4; mf++) {
        const int row = wm * 64 + mf * 16 + l16;
        af[mf] = *(const half8*)&As[row * 64 + (((kk * 4 + quad)) ^ (row & 7)) * 8];
      }
#pragma unroll
      for (int at = 0; at < 4; at++) {
        const int row = wn * 64 + at * 16 + l16;
        bf[at] = *(const half8*)&Bs[buf][row * 64 + (((kk * 4 + quad)) ^ (row & 7)) * 8];
      }
#pragma unroll
      for (int mf = 0; mf < 4; mf++)
#pragma unroll
        for (int at = 0; at < 4; at++)
          acc[mf][at] = __builtin_amdgcn_mfma_f32_16x16x32_f16(af[mf], bf[at], acc[mf][at], 0, 0, 0);
    }

    __builtin_amdgcn_sched_barrier(0);
    __builtin_amdgcn_s_barrier();   // all waves done reading As/Bs[buf]
    __builtin_amdgcn_sched_barrier(0);
  };

  int kt = 0;
  for (int s = 0; s < 31; ++s, kt += 64) kstep(kt, s & 1, false);
  kstep(kt, 31 & 1, true);

  float w4[4];
#pragma unroll
  for (int at = 0; at < 4; at++) w4[at] = wcom[a0 + wn * 64 + at * 16 + l16];

#pragma unroll
  for (int mf = 0; mf < 4; mf++) {
#pragma unroll
    for (int r = 0; r < 4; r++) {
      const int m  = m0 + wm * 64 + mf * 16 + quad * 4 + r;  // C/D: row=(lane>>4)*4+reg
      const int db = m / L_ - b0;
      float p = 0.f;
#pragma unroll
      for (int at = 0; at < 4; at++) {
        const float e = acc[mf][at][r] + decS[db][wn * 64 + at * 16 + l16];
        p = fmaf(fmaxf(e, 0.f), w4[at], p);
      }
      p += __shfl_xor(p, 1);
      p += __shfl_xor(p, 2);
      p += __shfl_xor(p, 4);
      p += __shfl_xor(p, 8);
      if (l16 == 0) atomicAdd(&scores[m], p);
    }
  }
}

// ---------------------------------------------------------------------------
// K_softmax: alpha[b,:] = softmax(scores[b,:]). 128 blocks x 256 thr, ~2us.
// ---------------------------------------------------------------------------
__global__ __launch_bounds__(256) void k_softmax(const float* __restrict__ scores,
                                                 float* __restrict__ alpha) {
  const int b = blockIdx.x, t = threadIdx.x;
  __shared__ float redm[4];
  __shared__ float reds[4];

  float s = (t < L_) ? scores[b * L_ + t] : -INFINITY;
  float m = s;
#pragma unroll
  for (int o = 32; o >= 1; o >>= 1) m = fmaxf(m, __shfl_xor(m, o));
  if ((t & 63) == 0) redm[t >> 6] = m;
  __syncthreads();
  m = fmaxf(fmaxf(redm[0], redm[1]), fmaxf(redm[2], redm[3]));
  float e = (t < L_) ? expf(s - m) : 0.f;
  float sum = e;
#pragma unroll
  for (int o = 32; o >= 1; o >>= 1) sum += __shfl_xor(sum, o);
  if ((t & 63) == 0) reds[t >> 6] = sum;
  __syncthreads();
  sum = reds[0] + reds[1] + reds[2] + reds[3];
  if (t < L_) alpha[b * L_ + t] = e / sum;
}

// ---------------------------------------------------------------------------
// K_attn: pure weighted sum over fp32 feat, reading precomputed alpha.
// grid (8 f-chunks, B) x 128 threads; two independent row streams.
// ---------------------------------------------------------------------------
__global__ __launch_bounds__(128) void k_attn_f32(const float* __restrict__ feat,
                                                  const float* __restrict__ alpha,
                                                  float* __restrict__ out) {
  const int fc = blockIdx.x, b = blockIdx.y, t = threadIdx.x;
  __shared__ float al[L_];

  al[t] = alpha[b * L_ + t];
  if (t < L_ - 128) al[t + 128] = alpha[b * L_ + t + 128];
  __syncthreads();

  const int f0 = fc * 256 + t * 2;
  const float2* fp = (const float2*)(feat + (size_t)b * L_ * F_ + f0);
  float a0x = 0.f, a0y = 0.f, a1x = 0.f, a1y = 0.f;
#pragma unroll 7
  for (int ll = 0; ll < 98; ll++) {
    const float2 v0 = fp[(size_t)ll * (F_ / 2)];
    const float2 v1 = fp[(size_t)(ll + 98) * (F_ / 2)];
    const float w0 = al[ll];
    const float w1 = al[ll + 98];
    a0x = fmaf(v0.x, w0, a0x);
    a0y = fmaf(v0.y, w0, a0y);
    a1x = fmaf(v1.x, w1, a1x);
    a1y = fmaf(v1.y, w1, a1y);
  }
  float2 o = { a0x + a1x, a0y + a1y };
  *(float2*)(out + (size_t)b * F_ + f0) = o;
}

// ---------------------------------------------------------------------------
// Fallback fp32 GEMM path (ws too small — effectively never taken)
// ---------------------------------------------------------------------------
__global__ __launch_bounds__(256) void k_scores_f32(const float* __restrict__ feat,
                                                    const float* __restrict__ Wenc,
                                                    const float* __restrict__ dec,
                                                    const float* __restrict__ wcom,
                                                    float* __restrict__ scores) {
  __shared__ float As[16][128];
  __shared__ float Bs[16][128];
  const int tid = threadIdx.x;
  const int m0 = blockIdx.x * 128;
  const int a0 = blockIdx.y * 128;
  const int tx = tid & 15;
  const int ty = tid >> 4;
  float acc[8][8];
#pragma unroll
  for (int i = 0; i < 8; i++)
#pragma unroll
    for (int j = 0; j < 8; j++) acc[i][j] = 0.f;
  for (int kt = 0; kt < F_; kt += 16) {
#pragma unroll
    for (int rep = 0; rep < 2; rep++) {
      const int idx = rep * 256 + tid;
      const int row = idx >> 2;
      const int kp  = (idx & 3) << 2;
      const float4 v = *(const float4*)(feat + (size_t)(m0 + row) * F_ + kt + kp);
      As[kp+0][row] = v.x; As[kp+1][row] = v.y; As[kp+2][row] = v.z; As[kp+3][row] = v.w;
      const float4 w = *(const float4*)(Wenc + (size_t)(a0 + row) * F_ + kt + kp);
      Bs[kp+0][row] = w.x; Bs[kp+1][row] = w.y; Bs[kp+2][row] = w.z; Bs[kp+3][row] = w.w;
    }
    __syncthreads();
#pragma unroll
    for (int k = 0; k < 16; k++) {
      float ar[8], br[8];
      *(float4*)&ar[0] = *(const float4*)&As[k][ty * 8];
      *(float4*)&ar[4] = *(const float4*)&As[k][ty * 8 + 4];
      *(float4*)&br[0] = *(const float4*)&Bs[k][tx * 8];
      *(float4*)&br[4] = *(const float4*)&Bs[k][tx * 8 + 4];
#pragma unroll
      for (int i = 0; i < 8; i++)
#pragma unroll
        for (int j = 0; j < 8; j++) acc[i][j] = fmaf(ar[i], br[j], acc[i][j]);
    }
    __syncthreads();
  }
  float w8[8];
  *(float4*)&w8[0] = *(const float4*)(wcom + a0 + tx * 8);
  *(float4*)&w8[4] = *(const float4*)(wcom + a0 + tx * 8 + 4);
#pragma unroll
  for (int i = 0; i < 8; i++) {
    const int m = m0 + ty * 8 + i;
    const int b = m / L_;
    const float* dp = dec + b * A_ + a0 + tx * 8;
    float p = 0.f;
#pragma unroll
    for (int j = 0; j < 8; j++) {
      const float e = acc[i][j] + dp[j];
      p = fmaf(fmaxf(e, 0.f), w8[j], p);
    }
    p += __shfl_xor(p, 1);
    p += __shfl_xor(p, 2);
    p += __shfl_xor(p, 4);
    p += __shfl_xor(p, 8);
    if (tx == 0) atomicAdd(&scores[m], p);
  }
}

__global__ __launch_bounds__(256) void k_dec_only(const float* __restrict__ hs,
                                                  const float* __restrict__ Wdec,
                                                  const float* __restrict__ bdec,
                                                  const float* __restrict__ benc,
                                                  float* __restrict__ dec,
                                                  float* __restrict__ scores) {
  const int b = blockIdx.x, t = threadIdx.x;
  const int g = b * 256 + t;
  if (g < ML_) scores[g] = 0.f;
  __shared__ float h[H_];
  h[t]       = hs[b * H_ + t];
  h[t + 256] = hs[b * H_ + t + 256];
  __syncthreads();
#pragma unroll
  for (int r = 0; r < 2; r++) {
    const int a = t + r * 256;
    float acc = bdec[a] + benc[a];
    const float4* wr = (const float4*)(Wdec + (size_t)a * H_);
#pragma unroll 4
    for (int k4 = 0; k4 < H_ / 4; k4++) {
      const float4 w = wr[k4];
      acc += w.x * h[4*k4] + w.y * h[4*k4+1] + w.z * h[4*k4+2] + w.w * h[4*k4+3];
    }
    dec[b * A_ + a] = acc;
  }
}

// ---------------------------------------------------------------------------
extern "C" void kernel_launch(void* const* d_in, const int* in_sizes, int n_in,
                              void* d_out, int out_size, void* d_ws, size_t ws_size,
                              hipStream_t stream) {
  const float* feat = (const float*)d_in[0];   // [B,L,F]
  const float* hs   = (const float*)d_in[1];   // [B,H]
  const float* Wenc = (const float*)d_in[2];   // [A,F]
  const float* benc = (const float*)d_in[3];   // [A]
  const float* Wdec = (const float*)d_in[4];   // [A,H]
  const float* bdec = (const float*)d_in[5];   // [A]
  const float* wcom = (const float*)d_in[6];   // [1,A]
  // d_in[7] = b_com: softmax-invariant, unused

  float* out   = (float*)d_out;                // [B*F] weighted ++ [B*L] alpha
  float* alpha = out + B_ * F_;
  float* dec    = (float*)d_ws;                // [B*A]
  float* scores = dec + B_ * A_;               // [B*L]

  const size_t need = (size_t)(B_ * A_ + ML_) * 4 + (size_t)A_ * F_ * 2;

  if (ws_size >= need) {
    _Float16* wH = (_Float16*)(scores + ML_);  // [A_, F_] f16
    k_prep<<<dim3(128), dim3(256), 0, stream>>>(
        (const float4*)Wenc, (half4v*)wH, hs, Wdec, bdec, benc, dec, scores);
    k_scores_mfma<<<dim3(784), dim3(256), 0, stream>>>(feat, wH, dec, wcom, scores);
  } else {
    k_dec_only<<<dim3(B_), dim3(256), 0, stream>>>(hs, Wdec, bdec, benc, dec, scores);
    k_scores_f32<<<dim3(ML_ / 128, A_ / 128), dim3(256), 0, stream>>>(feat, Wenc, dec, wcom, scores);
  }
  k_softmax<<<dim3(B_), dim3(256), 0, stream>>>(scores, alpha);
  k_attn_f32<<<dim3(8, B_), dim3(128), 0, stream>>>(feat, alpha, out);
}